// Round 14
// baseline (370.436 us; speedup 1.0000x reference)
//
// GLM4 attention block (B=1, L=2048, HID=4096, H=32, KV=2, D=128, ROT=64) on MI355X.
// Round 14: SPLIT-K=2 hypothesis test. Both GEMMs: blockIdx.z = K-half, NT=64,
//   bf16 partials; QKV partials -> qkv_post (sum+bias+RoPE); O partials -> oreduce.
//   All transposes+cast fused into one BW-bound preproc kernel (incl. Wo).
//   GEMM inner loop identical to r12 (BK=32, 2-buffer, 4 blocks/CU). Attn = r12.
#include <hip/hip_runtime.h>
#include <stdint.h>

#define L_SEQ 2048
#define HID   4096
#define NH    32
#define NKV   2
#define DH    128
#define NQKV  4608                     // H*D + 2*KV*D
#define QSCALE 0.088388347648318447f   // 128^-0.5

typedef __bf16 bf16x8 __attribute__((ext_vector_type(8)));
typedef float  f32x4  __attribute__((ext_vector_type(4)));

__device__ __forceinline__ unsigned short f2bf(float f) {
  union { float f; unsigned u; } cv; cv.f = f;
  unsigned u = cv.u;
  return (unsigned short)((u + 0x7fffu + ((u >> 16) & 1u)) >> 16);   // RNE, finite-only
}
__device__ __forceinline__ float bf2f(unsigned short h) {
  union { unsigned u; float f; } cv; cv.u = (unsigned)h << 16; return cv.f;
}
__device__ __forceinline__ unsigned pk2(float a, float b) {
  return (unsigned)f2bf(a) | ((unsigned)f2bf(b) << 16);
}

// async global->LDS, 16B per lane; LDS dest = wave-uniform base + lane*16
#define GLL16(gsrc, ldst)                                                              \
  __builtin_amdgcn_global_load_lds(                                                    \
      (const __attribute__((address_space(1))) unsigned int*)(gsrc),                   \
      (__attribute__((address_space(3))) unsigned int*)(ldst), 16, 0, 0)

// ---- shared transpose tile body: in (R,C) fp32 -> out (C,R) bf16, 64x64 tile
__device__ __forceinline__ void transpose_tile(const float* __restrict__ in,
                                               unsigned short* __restrict__ out,
                                               int R, int C, int bx, int by,
                                               float* tile /* [64*65] */, int tid) {
  const int c0 = bx * 64, r0 = by * 64;
  #pragma unroll
  for (int it = 0; it < 4; ++it) {
    int row = it * 16 + (tid >> 4);
    float4 v = *reinterpret_cast<const float4*>(&in[(size_t)(r0 + row) * C + c0 + (tid & 15) * 4]);
    tile[row * 65 + (tid & 15) * 4 + 0] = v.x;
    tile[row * 65 + (tid & 15) * 4 + 1] = v.y;
    tile[row * 65 + (tid & 15) * 4 + 2] = v.z;
    tile[row * 65 + (tid & 15) * 4 + 3] = v.w;
  }
  __syncthreads();
  #pragma unroll
  for (int it = 0; it < 8; ++it) {
    int c  = it * 8 + (tid >> 5);
    int rp = tid & 31;
    unsigned u = (unsigned)f2bf(tile[2 * rp * 65 + c]) |
                 ((unsigned)f2bf(tile[(2 * rp + 1) * 65 + c]) << 16);
    *reinterpret_cast<unsigned*>(&out[(size_t)(c0 + c) * R + r0 + 2 * rp]) = u;
  }
}

// ---------------------------------------------------------------- fused preproc (BW-bound work)
// [0,8192): cast x ; [8192,12288): tWq ; [12288,12544): tWk ; [12544,12800): tWv ;
// [12800,16896): tWo
__global__ __launch_bounds__(256) void preproc_kernel(const float* __restrict__ x,
                                                      unsigned short* __restrict__ xb,
                                                      const float* __restrict__ Wq,
                                                      const float* __restrict__ Wk,
                                                      const float* __restrict__ Wv,
                                                      const float* __restrict__ Wo,
                                                      unsigned short* __restrict__ Wqkvt,
                                                      unsigned short* __restrict__ Wot) {
  __shared__ __attribute__((aligned(16))) float tile[64 * 65];
  const int tid = threadIdx.x;
  int bid = blockIdx.x;
  if (bid < 8192) {
    int i = bid * 256 + tid;
    float4 v = reinterpret_cast<const float4*>(x)[i];
    ushort4 o;
    o.x = f2bf(v.x); o.y = f2bf(v.y); o.z = f2bf(v.z); o.w = f2bf(v.w);
    reinterpret_cast<ushort4*>(xb)[i] = o;
    return;
  }
  bid -= 8192;
  if (bid < 4096) {
    transpose_tile(Wq, Wqkvt, HID, HID, bid & 63, bid >> 6, tile, tid);
  } else if (bid < 4352) {
    bid -= 4096;
    transpose_tile(Wk, Wqkvt + (size_t)4096 * HID, HID, 256, bid & 3, bid >> 2, tile, tid);
  } else if (bid < 4608) {
    bid -= 4352;
    transpose_tile(Wv, Wqkvt + (size_t)4352 * HID, HID, 256, bid & 3, bid >> 2, tile, tid);
  } else {
    bid -= 4608;
    transpose_tile(Wo, Wot, HID, HID, bid & 63, bid >> 6, tile, tid);
  }
}

// vlin[g][l][128] bf16 -> vt[g][d][l] bf16 (64x64 tiles)
__global__ __launch_bounds__(256) void vtrans_kernel(const unsigned short* __restrict__ in,
                                                     unsigned short* __restrict__ out) {
  __shared__ unsigned short tile[64][72];
  const int l0 = blockIdx.x * 64, d0 = blockIdx.y * 64, g = blockIdx.z;
  const int tid = threadIdx.x;
  #pragma unroll
  for (int it = 0; it < 2; ++it) {
    int l = it * 32 + (tid >> 3);
    *reinterpret_cast<uint4*>(&tile[l][(tid & 7) * 8]) =
        *reinterpret_cast<const uint4*>(&in[((size_t)g * L_SEQ + l0 + l) * DH + d0 + (tid & 7) * 8]);
  }
  __syncthreads();
  #pragma unroll
  for (int it = 0; it < 2; ++it) {
    int d = it * 32 + (tid >> 3);
    unsigned short tmp[8];
    #pragma unroll
    for (int e = 0; e < 8; ++e) tmp[e] = tile[(tid & 7) * 8 + e][d];
    *reinterpret_cast<uint4*>(&out[((size_t)g * DH + d0 + d) * L_SEQ + l0 + (tid & 7) * 8]) =
        *reinterpret_cast<uint4*>(tmp);
  }
}

// ---------------------------------------------------------------- split-K GEMM
// Cp[kz][M][N] (bf16 partial) = A(M, K/2 slice) * Bt(N, K/2 slice)^T, kz = blockIdx.z.
// BM=BN=128, BK=32; 4 waves; 2-buffer LDS (32KB -> 4 blocks/CU); r12 schedule:
//   vmcnt(4) -> bar -> 8 frag reads -> lgkm(0) -> bar -> stage(t+2) -> 16 MFMA.
#define TBM 128
#define TBN 128
#define TBK 32

__global__ __launch_bounds__(256, 4) void gemmsk_kernel(const unsigned short* __restrict__ A,
                                                        const unsigned short* __restrict__ Bt,
                                                        unsigned short* __restrict__ Cp,
                                                        int M, int N, int K) {
  __shared__ __attribute__((aligned(16))) unsigned short As[2][TBM * TBK];
  __shared__ __attribute__((aligned(16))) unsigned short Bs[2][TBN * TBK];
  const int tid = threadIdx.x;
  const int wave = tid >> 6, lane = tid & 63;
  const int lg = lane >> 4, ll = lane & 15;
  const int wm = wave >> 1, wn = wave & 1;     // 2x2 wave grid, 64x64 each
  const int kz = blockIdx.z;
  const int kbase = kz * (K >> 1);
  const int NT = K >> 6;                        // (K/2)/32

  // XCD-chunked block swizzle within the kz plane (bijective when nwg%8==0)
  int gx = gridDim.x, nwg = gx * gridDim.y;
  int flat = blockIdx.y * gx + blockIdx.x;
  int bx = blockIdx.x, by = blockIdx.y;
  if ((nwg & 7) == 0) {
    int t = (flat & 7) * (nwg >> 3) + (flat >> 3);
    bx = t % gx; by = t / gx;
  }
  const int m0 = by * TBM, n0 = bx * TBN;

  f32x4 acc[4][4] = {};

  // buffer = 128 rows x 4 chunks(16B); physical chunk p = c ^ ((row>>1)&3)  [0 conflicts]
  auto stage = [&](int t, int buf) {
    const int k0 = kbase + t * TBK;
    #pragma unroll
    for (int i = 0; i < 2; ++i) {
      int ci  = (i * 4 + wave) * 64 + lane;     // 0..511
      int row = ci >> 2;
      int cg  = (ci & 3) ^ ((row >> 1) & 3);
      GLL16(A + (size_t)(m0 + row) * K + k0 + cg * 8, &As[buf][(i * 4 + wave) * 512]);
    }
    #pragma unroll
    for (int i = 0; i < 2; ++i) {
      int ci  = (i * 4 + wave) * 64 + lane;
      int row = ci >> 2;
      int cg  = (ci & 3) ^ ((row >> 1) & 3);
      GLL16(Bt + (size_t)(n0 + row) * K + k0 + cg * 8, &Bs[buf][(i * 4 + wave) * 512]);
    }
  };

  stage(0, 0);
  stage(1, 1);

  for (int t = 0; t < NT; ++t) {
    const int cur = t & 1;
    if (t + 1 < NT) asm volatile("s_waitcnt vmcnt(4)" ::: "memory");
    else            asm volatile("s_waitcnt vmcnt(0)" ::: "memory");
    __builtin_amdgcn_s_barrier();      // buf cur visible to all waves

    const unsigned short* Ac = &As[cur][0];
    const unsigned short* Bc = &Bs[cur][0];
    bf16x8 afr[4], bfr[4];
    #pragma unroll
    for (int i = 0; i < 4; ++i) {
      int ra = wm * 64 + i * 16 + ll;
      afr[i] = *reinterpret_cast<const bf16x8*>(
          &Ac[ra * 32 + ((lg ^ ((ra >> 1) & 3)) * 8)]);
      int rb = wn * 64 + i * 16 + ll;
      bfr[i] = *reinterpret_cast<const bf16x8*>(
          &Bc[rb * 32 + ((lg ^ ((rb >> 1) & 3)) * 8)]);
    }
    asm volatile("s_waitcnt lgkmcnt(0)" ::: "memory");
    __builtin_amdgcn_s_barrier();      // all waves done reading buf cur
    if (t + 2 < NT) stage(t + 2, cur); // refill vacated buffer (overlaps MFMA)

    __builtin_amdgcn_s_setprio(1);
    #pragma unroll
    for (int i = 0; i < 4; ++i)
      #pragma unroll
      for (int j = 0; j < 4; ++j)
        acc[i][j] = __builtin_amdgcn_mfma_f32_16x16x32_bf16(afr[i], bfr[j], acc[i][j], 0, 0, 0);
    __builtin_amdgcn_s_setprio(0);
  }

  unsigned short* Cz = Cp + (size_t)kz * M * N;
  #pragma unroll
  for (int i = 0; i < 4; ++i)
    #pragma unroll
    for (int j = 0; j < 4; ++j) {
      int col  = n0 + wn * 64 + j * 16 + ll;
      int rowb = m0 + wm * 64 + i * 16 + lg * 4;
      #pragma unroll
      for (int r = 0; r < 4; ++r)
        Cz[(size_t)(rowb + r) * N + col] = f2bf(acc[i][j][r]);
    }
}

// ---------------------------------------------------------------- QKV post: sum partials + bias + RoPE
// qp: [2][L][4608] bf16. grid (L, 36): y<32 -> Q head y ; 32,33 -> K ; 34,35 -> V.
__global__ __launch_bounds__(128) void qkv_post_kernel(const unsigned short* __restrict__ qp,
                                                       const float* __restrict__ bq,
                                                       const float* __restrict__ bk,
                                                       const float* __restrict__ bv,
                                                       const float* __restrict__ cosT,
                                                       const float* __restrict__ sinT,
                                                       unsigned short* __restrict__ qb,
                                                       unsigned short* __restrict__ kb,
                                                       unsigned short* __restrict__ vlin) {
  const unsigned short* p1 = qp + (size_t)L_SEQ * NQKV;
  int l = blockIdx.x, y = blockIdx.y, d = threadIdx.x;
  auto rd = [&](size_t idx) { return bf2f(qp[idx]) + bf2f(p1[idx]); };
  if (y < 34) {                                 // Q or K: bias + RoPE
    const bool isq = (y < 32);
    const int hh = isq ? y : (y - 32);
    const float* bias = isq ? bq : bk;
    size_t base = (size_t)l * NQKV + (isq ? 0 : 4096) + hh * DH;
    float v = rd(base + d) + bias[hh * DH + d];
    float o;
    if (d < 32) {
      float x2 = rd(base + d + 32) + bias[hh * DH + d + 32];
      o = v * cosT[l * 32 + d] - x2 * sinT[l * 32 + d];
    } else if (d < 64) {
      int i = d - 32;
      float x1 = rd(base + i) + bias[hh * DH + i];
      o = v * cosT[l * 32 + i] + x1 * sinT[l * 32 + i];
    } else {
      o = v;
    }
    if (isq) qb[((size_t)hh * L_SEQ + l) * DH + d] = f2bf(o * QSCALE);
    else     kb[((size_t)hh * L_SEQ + l) * DH + d] = f2bf(o);
  } else {                                      // V: bias -> vlin[g][l][d]
    int g = y - 34;
    float o = rd((size_t)l * NQKV + 4352 + g * DH + d) + bv[g * DH + d];
    vlin[((size_t)g * L_SEQ + l) * DH + d] = f2bf(o);
  }
}

// ---------------------------------------------------------------- O reduce: d_out = p0 + p1
__global__ __launch_bounds__(256) void oreduce_kernel(const unsigned short* __restrict__ op,
                                                      float* __restrict__ out) {
  const size_t n = (size_t)L_SEQ * HID;
  size_t i = (size_t)blockIdx.x * 256 + threadIdx.x;   // 8 elems per thread
  uint4 u0 = reinterpret_cast<const uint4*>(op)[i];
  uint4 u1 = reinterpret_cast<const uint4*>(op + n)[i];
  float o[8];
  unsigned a[4] = {u0.x, u0.y, u0.z, u0.w}, b[4] = {u1.x, u1.y, u1.z, u1.w};
  #pragma unroll
  for (int k = 0; k < 4; ++k) {
    union { unsigned u; float f; } lo0, hi0, lo1, hi1;
    lo0.u = a[k] << 16;         lo1.u = b[k] << 16;
    hi0.u = a[k] & 0xffff0000u; hi1.u = b[k] & 0xffff0000u;
    o[k * 2]     = lo0.f + lo1.f;
    o[k * 2 + 1] = hi0.f + hi1.f;
  }
  float4* dst = reinterpret_cast<float4*>(out + i * 8);
  dst[0] = make_float4(o[0], o[1], o[2], o[3]);
  dst[1] = make_float4(o[4], o[5], o[6], o[7]);
}

// ---------------------------------------------------------------- flash attention (r12, unchanged)
__global__ __launch_bounds__(256, 2) void attn_kernel(const unsigned short* __restrict__ qg,
                                                      const unsigned short* __restrict__ kb,
                                                      const unsigned short* __restrict__ vt,
                                                      unsigned short* __restrict__ ob) {
  __shared__ __attribute__((aligned(16))) unsigned short Ks[2][64 * 128];
  __shared__ __attribute__((aligned(16))) unsigned short Vs[2][128 * 64];

  const int pair = blockIdx.x, h = blockIdx.y;
  const int g = h >> 4;
  const int tid = threadIdx.x, wave = tid >> 6, lane = tid & 63;
  const int lg = lane >> 4, ll = lane & 15;

  const int krow = (lane >> 4);
  const int kcg0 = (lane & 15);
  const int vrow = (lane >> 3);
  const int vcg0 = (lane & 7);

  #pragma unroll
  for (int seg = 0; seg < 2; ++seg) {
    const int qt = seg ? (31 - pair) : pair;
    const int q0 = qt * 64 + wave * 16;

    bf16x8 qf[4];
    #pragma unroll
    for (int f = 0; f < 4; ++f)
      qf[f] = *reinterpret_cast<const bf16x8*>(
          qg + ((size_t)h * L_SEQ + q0 + ll) * DH + f * 32 + lg * 8);

    f32x4 of[8] = {};
    float m = -1e30f, lsum = 0.f;

    const int kvN = qt + 1;
    int cur = 0;

    #pragma unroll
    for (int c = 0; c < 4; ++c) {
      int issue = wave * 4 + c;
      int rk = issue * 4 + krow;
      GLL16(kb + ((size_t)g * L_SEQ + rk) * DH + (kcg0 ^ (rk & 7)) * 8, &Ks[0][issue * 512]);
      int rv = issue * 8 + vrow;
      GLL16(vt + ((size_t)g * DH + rv) * L_SEQ + (vcg0 ^ (rv & 7)) * 8, &Vs[0][issue * 512]);
    }
    __syncthreads();

    for (int t = 0; t < kvN; ++t) {
      if (t + 1 < kvN) {
        int kv1 = (t + 1) * 64;
        #pragma unroll
        for (int c = 0; c < 4; ++c) {
          int issue = wave * 4 + c;
          int rk = issue * 4 + krow;
          GLL16(kb + ((size_t)g * L_SEQ + kv1 + rk) * DH + (kcg0 ^ (rk & 7)) * 8,
                &Ks[cur ^ 1][issue * 512]);
          int rv = issue * 8 + vrow;
          GLL16(vt + ((size_t)g * DH + rv) * L_SEQ + kv1 + (vcg0 ^ (rv & 7)) * 8,
                &Vs[cur ^ 1][issue * 512]);
        }
      }

      f32x4 s[4] = {};
      const unsigned short* Kc = &Ks[cur][0];
      #pragma unroll
      for (int cf = 0; cf < 4; ++cf) {
        bf16x8 kf[4];
        #pragma unroll
        for (int f = 0; f < 4; ++f) {
          int rk = cf * 16 + ll;
          int cc = (f * 4 + lg) ^ (rk & 7);
          kf[f] = *reinterpret_cast<const bf16x8*>(&Kc[rk * 128 + cc * 8]);
        }
        __builtin_amdgcn_s_setprio(1);
        #pragma unroll
        for (int f = 0; f < 4; ++f)
          s[cf] = __builtin_amdgcn_mfma_f32_16x16x32_bf16(kf[f], qf[f], s[cf], 0, 0, 0);
        __builtin_amdgcn_s_setprio(0);
      }

      if (t == qt) {
        #pragma unroll
        for (int cf = 0; cf < 4; ++cf)
          #pragma unroll
          for (int r = 0; r < 4; ++r)
            if (cf * 16 + lg * 4 + r > wave * 16 + ll) s[cf][r] = -1e30f;
      }

      float pmax = -1e30f;
      #pragma unroll
      for (int cf = 0; cf < 4; ++cf)
        #pragma unroll
        for (int r = 0; r < 4; ++r) pmax = fmaxf(pmax, s[cf][r]);
      if (!__all(pmax - m <= 8.f)) {
        float mx = fmaxf(pmax, __shfl_xor(pmax, 16));
        mx = fmaxf(mx, __shfl_xor(mx, 32));
        float mnew = fmaxf(m, mx);
        float alpha = __expf(m - mnew);
        m = mnew;
        lsum *= alpha;
        float af[4];
        #pragma unroll
        for (int r = 0; r < 4; ++r) af[r] = __shfl(alpha, lg * 4 + r);
        #pragma unroll
        for (int ds = 0; ds < 8; ++ds)
          #pragma unroll
          for (int r = 0; r < 4; ++r) of[ds][r] *= af[r];
      }

      unsigned wlo[4], whi[4];
      float psum = 0.f;
      #pragma unroll
      for (int cf = 0; cf < 4; ++cf) {
        float p0 = __expf(s[cf][0] - m), p1 = __expf(s[cf][1] - m);
        float p2 = __expf(s[cf][2] - m), p3 = __expf(s[cf][3] - m);
        psum += (p0 + p1) + (p2 + p3);
        wlo[cf] = pk2(p0, p1);
        whi[cf] = pk2(p2, p3);
      }
      lsum += psum;

      bf16x8 pa[2];
      {
        const int src0 = ((lg & 1) << 5) + ll;
        const int src1 = src0 + 16;
        const bool hi = (lg & 2) != 0;
        #pragma unroll
        for (int ks = 0; ks < 2; ++ks) {
          int e0a = __shfl((int)wlo[ks * 2], src0);
          int e1a = __shfl((int)whi[ks * 2], src0);
          int e2a = __shfl((int)wlo[ks * 2], src1);
          int e3a = __shfl((int)whi[ks * 2], src1);
          int e0b = __shfl((int)wlo[ks * 2 + 1], src0);
          int e1b = __shfl((int)whi[ks * 2 + 1], src0);
          int e2b = __shfl((int)wlo[ks * 2 + 1], src1);
          int e3b = __shfl((int)whi[ks * 2 + 1], src1);
          union { int i[4]; bf16x8 v; } u;
          u.i[0] = hi ? e0b : e0a;
          u.i[1] = hi ? e1b : e1a;
          u.i[2] = hi ? e2b : e2a;
          u.i[3] = hi ? e3b : e3a;
          pa[ks] = u.v;
        }
      }

      const unsigned short* Vc = &Vs[cur][0];
      #pragma unroll
      for (int ds = 0; ds < 8; ++ds) {
        bf16x8 vf[2];
        #pragma unroll
        for (int ks = 0; ks < 2; ++ks) {
          int dl = ds * 16 + ll;
          int cc = (ks * 4 + lg) ^ (dl & 7);
          vf[ks] = *reinterpret_cast<const bf16x8*>(&Vc[dl * 64 + cc * 8]);
        }
        __builtin_amdgcn_s_setprio(1);
        #pragma unroll
        for (int ks = 0; ks < 2; ++ks)
          of[ds] = __builtin_amdgcn_mfma_f32_16x16x32_bf16(pa[ks], vf[ks], of[ds], 0, 0, 0);
        __builtin_amdgcn_s_setprio(0);
      }

      __syncthreads();
      cur ^= 1;
    }

    float tot = lsum + __shfl_xor(lsum, 16);
    tot += __shfl_xor(tot, 32);
    float inv = 1.f / tot;
    float invr[4];
    #pragma unroll
    for (int r = 0; r < 4; ++r) invr[r] = __shfl(inv, lg * 4 + r);
    #pragma unroll
    for (int ds = 0; ds < 8; ++ds)
      #pragma unroll
      for (int r = 0; r < 4; ++r) {
        int row = q0 + lg * 4 + r;
        ob[(size_t)row * (NH * DH) + h * DH + ds * 16 + ll] = f2bf(of[ds][r] * invr[r]);
      }
    __syncthreads();
  }
}

// ---------------------------------------------------------------- launch
extern "C" void kernel_launch(void* const* d_in, const int* in_sizes, int n_in,
                              void* d_out, int out_size, void* d_ws, size_t ws_size,
                              hipStream_t stream) {
  (void)in_sizes; (void)n_in; (void)out_size; (void)ws_size;
  const float* x    = (const float*)d_in[0];
  const float* Wq   = (const float*)d_in[1];
  const float* bq   = (const float*)d_in[2];
  const float* Wk   = (const float*)d_in[3];
  const float* bk   = (const float*)d_in[4];
  const float* Wv   = (const float*)d_in[5];
  const float* bv   = (const float*)d_in[6];
  const float* Wo   = (const float*)d_in[7];
  const float* cosT = (const float*)d_in[8];
  const float* sinT = (const float*)d_in[9];
  // d_in[10] = attention_mask: unused (causal mask computed arithmetically)

  char* ws = (char*)d_ws;
  size_t off = 0;
  auto alloc = [&](size_t bytes) { void* p = ws + off; off += (bytes + 255) & ~(size_t)255; return p; };
  unsigned short* xb      = (unsigned short*)alloc((size_t)L_SEQ * HID * 2);
  unsigned short* Wqkvt   = (unsigned short*)alloc((size_t)NQKV * HID * 2);
  unsigned short* Wot     = (unsigned short*)alloc((size_t)HID * HID * 2);
  unsigned short* qkvpart = (unsigned short*)alloc((size_t)2 * L_SEQ * NQKV * 2);  // [2][L][4608]
  unsigned short* qbuf    = (unsigned short*)alloc((size_t)NH * L_SEQ * DH * 2);
  unsigned short* kbuf    = (unsigned short*)alloc((size_t)NKV * L_SEQ * DH * 2);
  unsigned short* vlin    = (unsigned short*)alloc((size_t)NKV * L_SEQ * DH * 2);
  unsigned short* vtb     = (unsigned short*)alloc((size_t)NKV * DH * L_SEQ * 2);
  unsigned short* attno   = (unsigned short*)alloc((size_t)L_SEQ * HID * 2);
  unsigned short* opart   = qkvpart;   // alias: qkvpart dead after qkv_post (33.5MB <= 37.7MB)

  // fused BW pass: cast + all 4 weight transposes
  preproc_kernel<<<16896, 256, 0, stream>>>(x, xb, Wq, Wk, Wv, Wo, Wqkvt, Wot);

  // QKV split-K GEMM -> bf16 partials
  gemmsk_kernel<<<dim3(NQKV / TBN, L_SEQ / TBM, 2), 256, 0, stream>>>(
      xb, Wqkvt, qkvpart, L_SEQ, NQKV, HID);

  qkv_post_kernel<<<dim3(L_SEQ, 36), 128, 0, stream>>>(qkvpart, bq, bk, bv, cosT, sinT,
                                                       qbuf, kbuf, vlin);

  vtrans_kernel<<<dim3(L_SEQ / 64, DH / 64, NKV), 256, 0, stream>>>(vlin, vtb);

  attn_kernel<<<dim3(16, NH), 256, 0, stream>>>(qbuf, kbuf, vtb, attno);

  // O split-K GEMM -> bf16 partials, then reduce to fp32 d_out
  gemmsk_kernel<<<dim3(HID / TBN, L_SEQ / TBM, 2), 256, 0, stream>>>(
      attno, Wot, opart, L_SEQ, HID, HID);

  oreduce_kernel<<<(L_SEQ * HID / 8) / 256, 256, 0, stream>>>(opart, (float*)d_out);
}

// Round 15
// 311.997 us; speedup vs baseline: 1.1873x; 1.1873x over previous
//
// GLM4 attention block (B=1, L=2048, HID=4096, H=32, KV=2, D=128, ROT=64) on MI355X.
// Round 15: traffic-model move. GEMM tile 256x128 (8 waves, 512 thr, wave-tile 64x64),
//   BK=32, 2-buffer 48KB LDS -> 2 blocks/CU (16 waves/CU TLP), r12 schedule,
//   counted vmcnt(3). Staged bytes/FLOP -27% vs 128^2 (10.6 TB/s staging ceiling).
//   Fused preproc (cast + 4 transposes). Attn/vtrans/epilogues = r12. No split-K.
#include <hip/hip_runtime.h>
#include <stdint.h>

#define L_SEQ 2048
#define HID   4096
#define NH    32
#define NKV   2
#define DH    128
#define NQKV  4608                     // H*D + 2*KV*D
#define QSCALE 0.088388347648318447f   // 128^-0.5

typedef __bf16 bf16x8 __attribute__((ext_vector_type(8)));
typedef float  f32x4  __attribute__((ext_vector_type(4)));

__device__ __forceinline__ unsigned short f2bf(float f) {
  union { float f; unsigned u; } cv; cv.f = f;
  unsigned u = cv.u;
  return (unsigned short)((u + 0x7fffu + ((u >> 16) & 1u)) >> 16);   // RNE, finite-only
}
__device__ __forceinline__ float bf2f(unsigned short h) {
  union { unsigned u; float f; } cv; cv.u = (unsigned)h << 16; return cv.f;
}
__device__ __forceinline__ unsigned pk2(float a, float b) {
  return (unsigned)f2bf(a) | ((unsigned)f2bf(b) << 16);
}

// async global->LDS, 16B per lane; LDS dest = wave-uniform base + lane*16
#define GLL16(gsrc, ldst)                                                              \
  __builtin_amdgcn_global_load_lds(                                                    \
      (const __attribute__((address_space(1))) unsigned int*)(gsrc),                   \
      (__attribute__((address_space(3))) unsigned int*)(ldst), 16, 0, 0)

// ---- shared transpose tile body: in (R,C) fp32 -> out (C,R) bf16, 64x64 tile
__device__ __forceinline__ void transpose_tile(const float* __restrict__ in,
                                               unsigned short* __restrict__ out,
                                               int R, int C, int bx, int by,
                                               float* tile /* [64*65] */, int tid) {
  const int c0 = bx * 64, r0 = by * 64;
  #pragma unroll
  for (int it = 0; it < 4; ++it) {
    int row = it * 16 + (tid >> 4);
    float4 v = *reinterpret_cast<const float4*>(&in[(size_t)(r0 + row) * C + c0 + (tid & 15) * 4]);
    tile[row * 65 + (tid & 15) * 4 + 0] = v.x;
    tile[row * 65 + (tid & 15) * 4 + 1] = v.y;
    tile[row * 65 + (tid & 15) * 4 + 2] = v.z;
    tile[row * 65 + (tid & 15) * 4 + 3] = v.w;
  }
  __syncthreads();
  #pragma unroll
  for (int it = 0; it < 8; ++it) {
    int c  = it * 8 + (tid >> 5);
    int rp = tid & 31;
    unsigned u = (unsigned)f2bf(tile[2 * rp * 65 + c]) |
                 ((unsigned)f2bf(tile[(2 * rp + 1) * 65 + c]) << 16);
    *reinterpret_cast<unsigned*>(&out[(size_t)(c0 + c) * R + r0 + 2 * rp]) = u;
  }
}

// ---------------------------------------------------------------- fused preproc (BW-bound work)
// [0,8192): cast x ; [8192,12288): tWq ; [12288,12544): tWk ; [12544,12800): tWv ;
// [12800,16896): tWo
__global__ __launch_bounds__(256) void preproc_kernel(const float* __restrict__ x,
                                                      unsigned short* __restrict__ xb,
                                                      const float* __restrict__ Wq,
                                                      const float* __restrict__ Wk,
                                                      const float* __restrict__ Wv,
                                                      const float* __restrict__ Wo,
                                                      unsigned short* __restrict__ Wqkvt,
                                                      unsigned short* __restrict__ Wot) {
  __shared__ __attribute__((aligned(16))) float tile[64 * 65];
  const int tid = threadIdx.x;
  int bid = blockIdx.x;
  if (bid < 8192) {
    int i = bid * 256 + tid;
    float4 v = reinterpret_cast<const float4*>(x)[i];
    ushort4 o;
    o.x = f2bf(v.x); o.y = f2bf(v.y); o.z = f2bf(v.z); o.w = f2bf(v.w);
    reinterpret_cast<ushort4*>(xb)[i] = o;
    return;
  }
  bid -= 8192;
  if (bid < 4096) {
    transpose_tile(Wq, Wqkvt, HID, HID, bid & 63, bid >> 6, tile, tid);
  } else if (bid < 4352) {
    bid -= 4096;
    transpose_tile(Wk, Wqkvt + (size_t)4096 * HID, HID, 256, bid & 3, bid >> 2, tile, tid);
  } else if (bid < 4608) {
    bid -= 4352;
    transpose_tile(Wv, Wqkvt + (size_t)4352 * HID, HID, 256, bid & 3, bid >> 2, tile, tid);
  } else {
    bid -= 4608;
    transpose_tile(Wo, Wot, HID, HID, bid & 63, bid >> 6, tile, tid);
  }
}

// vlin[g][l][128] bf16 -> vt[g][d][l] bf16 (64x64 tiles)
__global__ __launch_bounds__(256) void vtrans_kernel(const unsigned short* __restrict__ in,
                                                     unsigned short* __restrict__ out) {
  __shared__ unsigned short tile[64][72];
  const int l0 = blockIdx.x * 64, d0 = blockIdx.y * 64, g = blockIdx.z;
  const int tid = threadIdx.x;
  #pragma unroll
  for (int it = 0; it < 2; ++it) {
    int l = it * 32 + (tid >> 3);
    *reinterpret_cast<uint4*>(&tile[l][(tid & 7) * 8]) =
        *reinterpret_cast<const uint4*>(&in[((size_t)g * L_SEQ + l0 + l) * DH + d0 + (tid & 7) * 8]);
  }
  __syncthreads();
  #pragma unroll
  for (int it = 0; it < 2; ++it) {
    int d = it * 32 + (tid >> 3);
    unsigned short tmp[8];
    #pragma unroll
    for (int e = 0; e < 8; ++e) tmp[e] = tile[(tid & 7) * 8 + e][d];
    *reinterpret_cast<uint4*>(&out[((size_t)g * DH + d0 + d) * L_SEQ + l0 + (tid & 7) * 8]) =
        *reinterpret_cast<uint4*>(tmp);
  }
}

// ---------------------------------------------------------------- GEMM  C(M,N) = A(M,K) * Bt(N,K)^T
// BM=256, BN=128, BK=32; 512 threads = 8 waves (4x2, wave-tile 64x64, acc[4][4]);
// 2-buffer LDS (48KB -> 2 blocks/CU, 16 waves/CU); r12 schedule:
//   vmcnt(3) -> bar -> 8 frag reads -> lgkm(0) -> bar -> stage(t+2) -> 16 MFMA.
// Stage = 3 GLL/wave (A:2 issues, B:1). Swizzle chunk p = c ^ ((row>>1)&3).
#define TBM 256
#define TBN 128
#define TBK 32

template <int MODE>
__global__ __launch_bounds__(512, 4) void gemm256_kernel(const unsigned short* __restrict__ A,
                                                         const unsigned short* __restrict__ Bt,
                                                         float* __restrict__ C,
                                                         const float* __restrict__ bq,
                                                         const float* __restrict__ bk,
                                                         const float* __restrict__ bv,
                                                         const float* __restrict__ cosT,
                                                         const float* __restrict__ sinT,
                                                         unsigned short* __restrict__ qb,
                                                         unsigned short* __restrict__ kb,
                                                         unsigned short* __restrict__ vlin,
                                                         int M, int N, int K) {
  __shared__ __attribute__((aligned(16))) unsigned short As[2][TBM * TBK];
  __shared__ __attribute__((aligned(16))) unsigned short Bs[2][TBN * TBK];
  const int tid = threadIdx.x;
  const int wave = tid >> 6, lane = tid & 63;
  const int lg = lane >> 4, ll = lane & 15;
  const int wm = wave >> 1, wn = wave & 1;     // 4x2 wave grid, 64x64 each

  // XCD-chunked block swizzle (bijective when nwg%8==0)
  int gx = gridDim.x, nwg = gx * gridDim.y;
  int flat = blockIdx.y * gx + blockIdx.x;
  int bx = blockIdx.x, by = blockIdx.y;
  if ((nwg & 7) == 0) {
    int t = (flat & 7) * (nwg >> 3) + (flat >> 3);
    bx = t % gx; by = t / gx;
  }
  const int m0 = by * TBM, n0 = bx * TBN;

  f32x4 acc[4][4] = {};
  const int NT = K >> 5;   // K/32 (=128 here)

  // A tile = 256 rows x 4 chunks = 1024 chunks (2 issues/wave);
  // B tile = 128 rows x 4 chunks =  512 chunks (1 issue/wave).
  // physical chunk p = c ^ ((row>>1)&3)  [0 conflicts, r12-verified]
  auto stage = [&](int t, int buf) {
    const int k0 = t * TBK;
    #pragma unroll
    for (int i = 0; i < 2; ++i) {
      int ci  = (wave * 2 + i) * 64 + lane;     // 0..1023
      int row = ci >> 2;                        // 0..255
      int cg  = (ci & 3) ^ ((row >> 1) & 3);
      GLL16(A + (size_t)(m0 + row) * K + k0 + cg * 8, &As[buf][(wave * 2 + i) * 512]);
    }
    {
      int ci  = wave * 64 + lane;               // 0..511
      int row = ci >> 2;                        // 0..127
      int cg  = (ci & 3) ^ ((row >> 1) & 3);
      GLL16(Bt + (size_t)(n0 + row) * K + k0 + cg * 8, &Bs[buf][wave * 512]);
    }
  };

  stage(0, 0);
  stage(1, 1);

  for (int t = 0; t < NT; ++t) {
    const int cur = t & 1;
    if (t + 1 < NT) asm volatile("s_waitcnt vmcnt(3)" ::: "memory");
    else            asm volatile("s_waitcnt vmcnt(0)" ::: "memory");
    __builtin_amdgcn_s_barrier();      // buf cur visible to all waves

    const unsigned short* Ac = &As[cur][0];
    const unsigned short* Bc = &Bs[cur][0];
    bf16x8 afr[4], bfr[4];
    #pragma unroll
    for (int i = 0; i < 4; ++i) {
      int ra = wm * 64 + i * 16 + ll;
      afr[i] = *reinterpret_cast<const bf16x8*>(
          &Ac[ra * 32 + ((lg ^ ((ra >> 1) & 3)) * 8)]);
      int rb = wn * 64 + i * 16 + ll;
      bfr[i] = *reinterpret_cast<const bf16x8*>(
          &Bc[rb * 32 + ((lg ^ ((rb >> 1) & 3)) * 8)]);
    }
    asm volatile("s_waitcnt lgkmcnt(0)" ::: "memory");
    __builtin_amdgcn_s_barrier();      // all waves done reading buf cur
    if (t + 2 < NT) stage(t + 2, cur); // refill vacated buffer (overlaps MFMA)

    __builtin_amdgcn_s_setprio(1);
    #pragma unroll
    for (int i = 0; i < 4; ++i)
      #pragma unroll
      for (int j = 0; j < 4; ++j)
        acc[i][j] = __builtin_amdgcn_mfma_f32_16x16x32_bf16(afr[i], bfr[j], acc[i][j], 0, 0, 0);
    __builtin_amdgcn_s_setprio(0);
  }

  if (MODE == 0) {
    #pragma unroll
    for (int i = 0; i < 4; ++i)
      #pragma unroll
      for (int j = 0; j < 4; ++j) {
        int col  = n0 + wn * 64 + j * 16 + ll;
        int rowb = m0 + wm * 64 + i * 16 + lg * 4;
        #pragma unroll
        for (int r = 0; r < 4; ++r)
          C[(size_t)(rowb + r) * N + col] = acc[i][j][r];
      }
  } else {
    // Fused QKV epilogue: tile n0 covers exactly one 128-wide head slice.
    const int region = (n0 < 4096) ? 0 : ((n0 < 4352) ? 1 : 2);
    const int hh = (region == 0) ? (n0 >> 7) : ((region == 1) ? ((n0 - 4096) >> 7) : ((n0 - 4352) >> 7));
    const float* bias = (region == 0) ? bq : ((region == 1) ? bk : bv);
    #pragma unroll
    for (int j = 0; j < 4; ++j) {
      float bj = bias[hh * DH + wn * 64 + j * 16 + ll];
      #pragma unroll
      for (int i = 0; i < 4; ++i)
        #pragma unroll
        for (int r = 0; r < 4; ++r) acc[i][j][r] += bj;
    }
    // RoPE on wn==0 half (d<64): pairs (j, j^2), freq idx (j&1)*16+ll
    if (region < 2 && wn == 0) {
      #pragma unroll
      for (int i = 0; i < 4; ++i)
        #pragma unroll
        for (int r = 0; r < 4; ++r) {
          int l = m0 + wm * 64 + i * 16 + lg * 4 + r;
          float c0 = cosT[l * 32 + ll],      s0 = sinT[l * 32 + ll];
          float c1 = cosT[l * 32 + 16 + ll], s1 = sinT[l * 32 + 16 + ll];
          float x10 = acc[i][0][r], x20 = acc[i][2][r];
          float x11 = acc[i][1][r], x21 = acc[i][3][r];
          acc[i][0][r] = x10 * c0 - x20 * s0;
          acc[i][2][r] = x20 * c0 + x10 * s0;
          acc[i][1][r] = x11 * c1 - x21 * s1;
          acc[i][3][r] = x21 * c1 + x11 * s1;
        }
    }
    const float scale = (region == 0) ? QSCALE : 1.f;
    unsigned short* dst = (region == 0) ? qb : ((region == 1) ? kb : vlin);
    #pragma unroll
    for (int i = 0; i < 4; ++i)
      #pragma unroll
      for (int j = 0; j < 4; ++j) {
        int d = wn * 64 + j * 16 + ll;
        #pragma unroll
        for (int r = 0; r < 4; ++r) {
          int l = m0 + wm * 64 + i * 16 + lg * 4 + r;
          dst[((size_t)hh * L_SEQ + l) * DH + d] = f2bf(acc[i][j][r] * scale);
        }
      }
  }
}

// ---------------------------------------------------------------- flash attention (r12, unchanged)
__global__ __launch_bounds__(256, 2) void attn_kernel(const unsigned short* __restrict__ qg,
                                                      const unsigned short* __restrict__ kb,
                                                      const unsigned short* __restrict__ vt,
                                                      unsigned short* __restrict__ ob) {
  __shared__ __attribute__((aligned(16))) unsigned short Ks[2][64 * 128];
  __shared__ __attribute__((aligned(16))) unsigned short Vs[2][128 * 64];

  const int pair = blockIdx.x, h = blockIdx.y;
  const int g = h >> 4;
  const int tid = threadIdx.x, wave = tid >> 6, lane = tid & 63;
  const int lg = lane >> 4, ll = lane & 15;

  const int krow = (lane >> 4);
  const int kcg0 = (lane & 15);
  const int vrow = (lane >> 3);
  const int vcg0 = (lane & 7);

  #pragma unroll
  for (int seg = 0; seg < 2; ++seg) {
    const int qt = seg ? (31 - pair) : pair;
    const int q0 = qt * 64 + wave * 16;

    bf16x8 qf[4];
    #pragma unroll
    for (int f = 0; f < 4; ++f)
      qf[f] = *reinterpret_cast<const bf16x8*>(
          qg + ((size_t)h * L_SEQ + q0 + ll) * DH + f * 32 + lg * 8);

    f32x4 of[8] = {};
    float m = -1e30f, lsum = 0.f;

    const int kvN = qt + 1;
    int cur = 0;

    #pragma unroll
    for (int c = 0; c < 4; ++c) {
      int issue = wave * 4 + c;
      int rk = issue * 4 + krow;
      GLL16(kb + ((size_t)g * L_SEQ + rk) * DH + (kcg0 ^ (rk & 7)) * 8, &Ks[0][issue * 512]);
      int rv = issue * 8 + vrow;
      GLL16(vt + ((size_t)g * DH + rv) * L_SEQ + (vcg0 ^ (rv & 7)) * 8, &Vs[0][issue * 512]);
    }
    __syncthreads();

    for (int t = 0; t < kvN; ++t) {
      if (t + 1 < kvN) {
        int kv1 = (t + 1) * 64;
        #pragma unroll
        for (int c = 0; c < 4; ++c) {
          int issue = wave * 4 + c;
          int rk = issue * 4 + krow;
          GLL16(kb + ((size_t)g * L_SEQ + kv1 + rk) * DH + (kcg0 ^ (rk & 7)) * 8,
                &Ks[cur ^ 1][issue * 512]);
          int rv = issue * 8 + vrow;
          GLL16(vt + ((size_t)g * DH + rv) * L_SEQ + kv1 + (vcg0 ^ (rv & 7)) * 8,
                &Vs[cur ^ 1][issue * 512]);
        }
      }

      f32x4 s[4] = {};
      const unsigned short* Kc = &Ks[cur][0];
      #pragma unroll
      for (int cf = 0; cf < 4; ++cf) {
        bf16x8 kf[4];
        #pragma unroll
        for (int f = 0; f < 4; ++f) {
          int rk = cf * 16 + ll;
          int cc = (f * 4 + lg) ^ (rk & 7);
          kf[f] = *reinterpret_cast<const bf16x8*>(&Kc[rk * 128 + cc * 8]);
        }
        __builtin_amdgcn_s_setprio(1);
        #pragma unroll
        for (int f = 0; f < 4; ++f)
          s[cf] = __builtin_amdgcn_mfma_f32_16x16x32_bf16(kf[f], qf[f], s[cf], 0, 0, 0);
        __builtin_amdgcn_s_setprio(0);
      }

      if (t == qt) {
        #pragma unroll
        for (int cf = 0; cf < 4; ++cf)
          #pragma unroll
          for (int r = 0; r < 4; ++r)
            if (cf * 16 + lg * 4 + r > wave * 16 + ll) s[cf][r] = -1e30f;
      }

      float pmax = -1e30f;
      #pragma unroll
      for (int cf = 0; cf < 4; ++cf)
        #pragma unroll
        for (int r = 0; r < 4; ++r) pmax = fmaxf(pmax, s[cf][r]);
      if (!__all(pmax - m <= 8.f)) {
        float mx = fmaxf(pmax, __shfl_xor(pmax, 16));
        mx = fmaxf(mx, __shfl_xor(mx, 32));
        float mnew = fmaxf(m, mx);
        float alpha = __expf(m - mnew);
        m = mnew;
        lsum *= alpha;
        float af[4];
        #pragma unroll
        for (int r = 0; r < 4; ++r) af[r] = __shfl(alpha, lg * 4 + r);
        #pragma unroll
        for (int ds = 0; ds < 8; ++ds)
          #pragma unroll
          for (int r = 0; r < 4; ++r) of[ds][r] *= af[r];
      }

      unsigned wlo[4], whi[4];
      float psum = 0.f;
      #pragma unroll
      for (int cf = 0; cf < 4; ++cf) {
        float p0 = __expf(s[cf][0] - m), p1 = __expf(s[cf][1] - m);
        float p2 = __expf(s[cf][2] - m), p3 = __expf(s[cf][3] - m);
        psum += (p0 + p1) + (p2 + p3);
        wlo[cf] = pk2(p0, p1);
        whi[cf] = pk2(p2, p3);
      }
      lsum += psum;

      bf16x8 pa[2];
      {
        const int src0 = ((lg & 1) << 5) + ll;
        const int src1 = src0 + 16;
        const bool hi = (lg & 2) != 0;
        #pragma unroll
        for (int ks = 0; ks < 2; ++ks) {
          int e0a = __shfl((int)wlo[ks * 2], src0);
          int e1a = __shfl((int)whi[ks * 2], src0);
          int e2a = __shfl((int)wlo[ks * 2], src1);
          int e3a = __shfl((int)whi[ks * 2], src1);
          int e0b = __shfl((int)wlo[ks * 2 + 1], src0);
          int e1b = __shfl((int)whi[ks * 2 + 1], src0);
          int e2b = __shfl((int)wlo[ks * 2 + 1], src1);
          int e3b = __shfl((int)whi[ks * 2 + 1], src1);
          union { int i[4]; bf16x8 v; } u;
          u.i[0] = hi ? e0b : e0a;
          u.i[1] = hi ? e1b : e1a;
          u.i[2] = hi ? e2b : e2a;
          u.i[3] = hi ? e3b : e3a;
          pa[ks] = u.v;
        }
      }

      const unsigned short* Vc = &Vs[cur][0];
      #pragma unroll
      for (int ds = 0; ds < 8; ++ds) {
        bf16x8 vf[2];
        #pragma unroll
        for (int ks = 0; ks < 2; ++ks) {
          int dl = ds * 16 + ll;
          int cc = (ks * 4 + lg) ^ (dl & 7);
          vf[ks] = *reinterpret_cast<const bf16x8*>(&Vc[dl * 64 + cc * 8]);
        }
        __builtin_amdgcn_s_setprio(1);
        #pragma unroll
        for (int ks = 0; ks < 2; ++ks)
          of[ds] = __builtin_amdgcn_mfma_f32_16x16x32_bf16(pa[ks], vf[ks], of[ds], 0, 0, 0);
        __builtin_amdgcn_s_setprio(0);
      }

      __syncthreads();
      cur ^= 1;
    }

    float tot = lsum + __shfl_xor(lsum, 16);
    tot += __shfl_xor(tot, 32);
    float inv = 1.f / tot;
    float invr[4];
    #pragma unroll
    for (int r = 0; r < 4; ++r) invr[r] = __shfl(inv, lg * 4 + r);
    #pragma unroll
    for (int ds = 0; ds < 8; ++ds)
      #pragma unroll
      for (int r = 0; r < 4; ++r) {
        int row = q0 + lg * 4 + r;
        ob[(size_t)row * (NH * DH) + h * DH + ds * 16 + ll] = f2bf(of[ds][r] * invr[r]);
      }
    __syncthreads();
  }
}

// ---------------------------------------------------------------- launch
extern "C" void kernel_launch(void* const* d_in, const int* in_sizes, int n_in,
                              void* d_out, int out_size, void* d_ws, size_t ws_size,
                              hipStream_t stream) {
  (void)in_sizes; (void)n_in; (void)out_size; (void)ws_size;
  const float* x    = (const float*)d_in[0];
  const float* Wq   = (const float*)d_in[1];
  const float* bq   = (const float*)d_in[2];
  const float* Wk   = (const float*)d_in[3];
  const float* bk   = (const float*)d_in[4];
  const float* Wv   = (const float*)d_in[5];
  const float* bv   = (const float*)d_in[6];
  const float* Wo   = (const float*)d_in[7];
  const float* cosT = (const float*)d_in[8];
  const float* sinT = (const float*)d_in[9];
  // d_in[10] = attention_mask: unused (causal mask computed arithmetically)

  char* ws = (char*)d_ws;
  size_t off = 0;
  auto alloc = [&](size_t bytes) { void* p = ws + off; off += (bytes + 255) & ~(size_t)255; return p; };
  unsigned short* xb    = (unsigned short*)alloc((size_t)L_SEQ * HID * 2);
  unsigned short* Wqkvt = (unsigned short*)alloc((size_t)NQKV * HID * 2);
  unsigned short* Wot   = (unsigned short*)alloc((size_t)HID * HID * 2);
  unsigned short* qbuf  = (unsigned short*)alloc((size_t)NH * L_SEQ * DH * 2);
  unsigned short* kbuf  = (unsigned short*)alloc((size_t)NKV * L_SEQ * DH * 2);
  unsigned short* vlin  = (unsigned short*)alloc((size_t)NKV * L_SEQ * DH * 2);
  unsigned short* vtb   = (unsigned short*)alloc((size_t)NKV * DH * L_SEQ * 2);
  unsigned short* attno = (unsigned short*)alloc((size_t)L_SEQ * HID * 2);

  // fused BW pass: cast + all 4 weight transposes
  preproc_kernel<<<16896, 256, 0, stream>>>(x, xb, Wq, Wk, Wv, Wo, Wqkvt, Wot);

  // QKV GEMM (256x128 tiles) with fused bias+RoPE epilogue -> qbuf, kbuf, vlin
  gemm256_kernel<1><<<dim3(NQKV / TBN, L_SEQ / TBM), 512, 0, stream>>>(
      xb, Wqkvt, nullptr, bq, bk, bv, cosT, sinT, qbuf, kbuf, vlin, L_SEQ, NQKV, HID);

  vtrans_kernel<<<dim3(L_SEQ / 64, DH / 64, NKV), 256, 0, stream>>>(vlin, vtb);

  attn_kernel<<<dim3(16, NH), 256, 0, stream>>>(qbuf, kbuf, vtb, attno);

  gemm256_kernel<0><<<dim3(HID / TBN, L_SEQ / TBM), 512, 0, stream>>>(
      attno, Wot, (float*)d_out, nullptr, nullptr, nullptr, nullptr, nullptr,
      nullptr, nullptr, nullptr, L_SEQ, HID, HID);
}